// Round 5
// baseline (602.831 us; speedup 1.0000x reference)
//
#include <hip/hip_runtime.h>
#include <hip/hip_bf16.h>

// TransformerShardA: 2-layer GPT-2 shard. B=1, S=2048, D=768, H=12, hd=64,
// FFN=3072. Inputs f32 (+int idx), output f32 [1,2048,768].
//
// Round 11 (session R4->R5): GEMM counted-vmcnt pipeline, attention frozen.
//  - BK=32, THREE LDS buffers (48KB/36KB), depth-3 software pipeline:
//    step t: STAGE(t+2) -> ds_read+MFMA(buf t) -> s_waitcnt vmcnt(NL) -> raw
//    s_barrier. vmcnt counts only the newest NL loads (stage t+2) as allowed
//    outstanding -> stage(t+1) proven complete for THIS wave pre-barrier ->
//    post-barrier all waves' t+1 resident. Never vmcnt(0) in main loop (T4).
//    sched_barrier(0) fences around asm waits/barriers (rule 18 / m152).
//  - T5 setprio(1) around MFMA cluster (2 blocks/CU -> role diversity).
//  - ln_kernel: 16 barriers -> 2 (wave shfl_xor reduce + 4-word LDS).
//  - embed merged into transpose_all (-1 dispatch).

#define SEQ 2048
#define DIM 768
#define NH 12
#define HD 64
#define FFN 3072
#define QKVD (3 * DIM)

typedef __attribute__((ext_vector_type(8))) short short8;
typedef __attribute__((ext_vector_type(4))) float f32x4;

#define VMCNT(n) asm volatile("s_waitcnt vmcnt(" #n ")" ::: "memory")
#define SCHED0() __builtin_amdgcn_sched_barrier(0)

__device__ __forceinline__ ushort bf16bits(float v) {
    __hip_bfloat16 hb = __float2bfloat16(v);
    return *reinterpret_cast<ushort*>(&hb);
}

// async 16B global->LDS (gfx950 global_load_lds_dwordx4)
__device__ __forceinline__ void gload_lds16(const ushort* g, ushort* l) {
    __builtin_amdgcn_global_load_lds(
        (const __attribute__((address_space(1))) void*)g,
        (__attribute__((address_space(3))) void*)l, 16, 0, 0);
}

// ------- merged: weight transpose W[K,N] f32 -> WT[N,K] bf16, + embedding ---
// blocks [0,13824): transposes. blocks [13824,19968): embed (x = emb[idx]+pe).
__global__ void transpose_all(
        const float* __restrict__ qkv_w, const float* __restrict__ out_w,
        const float* __restrict__ w1, const float* __restrict__ w2,
        __hip_bfloat16* __restrict__ qkv_wT, __hip_bfloat16* __restrict__ out_wT,
        __hip_bfloat16* __restrict__ w1T, __hip_bfloat16* __restrict__ w2T,
        const int* __restrict__ idx, const float* __restrict__ emb,
        const float* __restrict__ pe, float* __restrict__ x) {
    int b = blockIdx.x;
    if (b >= 13824) {                       // ---- embedding ----
        int i = (b - 13824) * 256 + threadIdx.x;
        int s = i / DIM;
        int d = i - s * DIM;
        x[i] = emb[idx[s] * DIM + d] + pe[i];
        return;
    }
    __shared__ float t[32][33];
    const float* W; __hip_bfloat16* T; int K, N, nx;
    if (b < 3456)        { W = qkv_w; T = qkv_wT; K = 768;  N = 2304; nx = 72; }
    else if (b < 4608)   { b -= 3456; W = out_w; T = out_wT; K = 768; N = 768; nx = 24; }
    else if (b < 9216)   { b -= 4608; W = w1;    T = w1T;   K = 768;  N = 3072; nx = 96; }
    else                 { b -= 9216; W = w2;    T = w2T;   K = 3072; N = 768;  nx = 24; }
    int ny = K / 32;
    int bz = b / (nx * ny);
    int rem = b - bz * (nx * ny);
    int by = rem / nx, bx = rem - by * nx;

    const float* Wp = W + (size_t)bz * K * N;
    __hip_bfloat16* Tp = T + (size_t)bz * K * N;
    int k0 = by * 32, n0 = bx * 32;
    int r = threadIdx.x >> 3, c4 = (threadIdx.x & 7) * 4;
    float4 v = *(const float4*)&Wp[(size_t)(k0 + r) * N + n0 + c4];
    t[r][c4 + 0] = v.x; t[r][c4 + 1] = v.y; t[r][c4 + 2] = v.z; t[r][c4 + 3] = v.w;
    __syncthreads();
    __hip_bfloat16* dst = &Tp[(size_t)(n0 + r) * K + k0 + c4];
#pragma unroll
    for (int j = 0; j < 4; ++j) dst[j] = __float2bfloat16(t[c4 + j][r]);
}

// ---------------- LayerNorm (one block per row), writes bf16 ----------------
// wave shfl_xor reduction + 4-word LDS: 2 barriers total (was 16).
__global__ void ln_kernel(const float* __restrict__ x,
                          const float* __restrict__ sc,
                          const float* __restrict__ bi,
                          __hip_bfloat16* __restrict__ h) {
    int row = blockIdx.x, tid = threadIdx.x;
    int w = tid >> 6;
    int lane = tid & 63;
    __shared__ float ws[4], ws2[4];
    const float* xr = x + row * DIM;
    float v[3];
#pragma unroll
    for (int i = 0; i < 3; ++i) v[i] = xr[tid + i * 256];
    float s = v[0] + v[1] + v[2];
#pragma unroll
    for (int off = 32; off > 0; off >>= 1) s += __shfl_xor(s, off);
    if (lane == 0) ws[w] = s;
    __syncthreads();
    float mean = (ws[0] + ws[1] + ws[2] + ws[3]) * (1.0f / DIM);
    float q = 0.f;
#pragma unroll
    for (int i = 0; i < 3; ++i) { float d = v[i] - mean; q += d * d; }
#pragma unroll
    for (int off = 32; off > 0; off >>= 1) q += __shfl_xor(q, off);
    if (lane == 0) ws2[w] = q;
    __syncthreads();
    float rstd = rsqrtf((ws2[0] + ws2[1] + ws2[2] + ws2[3]) * (1.0f / DIM) + 1e-5f);
#pragma unroll
    for (int i = 0; i < 3; ++i) {
        int d = tid + i * 256;
        h[row * DIM + d] = __float2bfloat16((v[i] - mean) * rstd * sc[d] + bi[d]);
    }
}

// ---------------- bf16 MFMA GEMM: C = [res +] act(A@W + bias) ---------------
// 128xBN tile, 4 waves (2x2), BK=32, 3 LDS buffers, depth-3 counted-vmcnt
// pipeline (T3/T4): per K-step issue STAGE(t+2), compute buf t, then
// s_waitcnt vmcnt(NL) (stage t+1 complete, t+2 allowed in flight) + raw
// s_barrier. LDS layout linear [row][32] (b128 reads inherently 8-phase
// balanced). NL = loads/thread/step: 4 (BN=128) or 3 (BN=64).
template <int BN, bool GELU, bool RES, bool OUTBF16>
__global__ __launch_bounds__(256) void mfma_gemm(
        const ushort* __restrict__ A, const ushort* __restrict__ WT,
        const float* __restrict__ bias, const float* __restrict__ res,
        void* __restrict__ Cout, int M, int N, int K) {
    constexpr int NT = BN / 32;          // B-frags per wave: 4 or 2
    constexpr int NAC = 2;               // A chunks/thread (128*32/8/256)
    constexpr int NBC = BN / 64;         // B chunks/thread: 2 or 1
    __shared__ alignas(16) ushort As[3][128 * 32];
    __shared__ alignas(16) ushort Bs[3][BN * 32];
    int tid = threadIdx.x;
    int w = tid >> 6, lane = tid & 63;
    int wm = (w >> 1) * 64, wn = (w & 1) * (BN / 2);
    int bm = blockIdx.y * 128, bn = blockIdx.x * BN;
    int lm = lane & 15, quad = lane >> 4, q8 = quad * 8;

    f32x4 acc[4][NT];
#pragma unroll
    for (int i = 0; i < 4; ++i)
#pragma unroll
        for (int j = 0; j < NT; ++j) acc[i][j] = {0.f, 0.f, 0.f, 0.f};

    // staging: chunk c -> row c>>2, col chunk c&3 (4 chunks of 8 elem per row)
    int cA[NAC], cB[NBC];
    const ushort* gA[NAC];
    const ushort* gB[NBC];
#pragma unroll
    for (int i = 0; i < NAC; ++i) {
        cA[i] = i * 256 + tid;
        gA[i] = &A[(size_t)(bm + (cA[i] >> 2)) * K + (cA[i] & 3) * 8];
    }
#pragma unroll
    for (int i = 0; i < NBC; ++i) {
        cB[i] = i * 256 + tid;
        gB[i] = &WT[(size_t)(bn + (cB[i] >> 2)) * K + (cB[i] & 3) * 8];
    }

    const int nk = K >> 5;

#define STAGE(T, SP)                                                   \
    do {                                                               \
        int _ko = (T) * 32;                                            \
        _Pragma("unroll")                                              \
        for (int _i = 0; _i < NAC; ++_i)                               \
            gload_lds16(gA[_i] + _ko, &As[SP][cA[_i] * 8]);            \
        _Pragma("unroll")                                              \
        for (int _i = 0; _i < NBC; ++_i)                               \
            gload_lds16(gB[_i] + _ko, &Bs[SP][cB[_i] * 8]);            \
    } while (0)

    // prologue: stage steps 0,1; wait for step 0 (leave step 1 in flight)
    STAGE(0, 0);
    STAGE(1, 1);
    if constexpr (NAC + NBC == 4) VMCNT(4); else VMCNT(3);
    SCHED0();
    __builtin_amdgcn_s_barrier();
    SCHED0();

    int bp = 0, sp = 2;
    for (int t = 0; t < nk; ++t) {
        if (t + 2 < nk) STAGE(t + 2, sp);
        SCHED0();   // keep stage issue ahead of compute

        short8 af[4], bw[NT];
#pragma unroll
        for (int mt = 0; mt < 4; ++mt)
            af[mt] = *(const short8*)&As[bp][(wm + mt * 16 + lm) * 32 + q8];
#pragma unroll
        for (int nt = 0; nt < NT; ++nt)
            bw[nt] = *(const short8*)&Bs[bp][(wn + nt * 16 + lm) * 32 + q8];

        __builtin_amdgcn_s_setprio(1);
#pragma unroll
        for (int mt = 0; mt < 4; ++mt)
#pragma unroll
            for (int nt = 0; nt < NT; ++nt)
                acc[mt][nt] = __builtin_amdgcn_mfma_f32_16x16x32_bf16(
                    af[mt], bw[nt], acc[mt][nt], 0, 0, 0);
        __builtin_amdgcn_s_setprio(0);

        // own stage(t+1) complete before barrier; stage(t+2) stays in flight
        if (t < nk - 2) {
            if constexpr (NAC + NBC == 4) VMCNT(4); else VMCNT(3);
        } else {
            VMCNT(0);
        }
        SCHED0();
        __builtin_amdgcn_s_barrier();
        SCHED0();
        bp = (bp == 2) ? 0 : bp + 1;
        sp = (sp == 2) ? 0 : sp + 1;
    }
#undef STAGE

#pragma unroll
    for (int nt = 0; nt < NT; ++nt) {
        int col = bn + wn + nt * 16 + lm;
        float bv = bias[col];
#pragma unroll
        for (int mt = 0; mt < 4; ++mt) {
            int rowb = bm + wm + mt * 16 + (q8 >> 1);
#pragma unroll
            for (int r = 0; r < 4; ++r) {
                int row = rowb + r;
                float v = acc[mt][nt][r] + bv;
                if (GELU) v = 0.5f * v * (1.0f + erff(v * 0.70710678118654752f));
                if (RES) v += res[(size_t)row * N + col];
                if (OUTBF16)
                    ((__hip_bfloat16*)Cout)[(size_t)row * N + col] = __float2bfloat16(v);
                else
                    ((float*)Cout)[(size_t)row * N + col] = v;
            }
        }
    }
}

// ---------------- MFMA flash attention (unchanged from R3) ----------------
__global__ __launch_bounds__(256) void flash_attn_kernel(
        const ushort* __restrict__ qkv, ushort* __restrict__ o) {
    int bi = blockIdx.x;
    int qt = 31 - bi / NH, head = bi % NH;
    int tid = threadIdx.x, w = tid >> 6, lane = tid & 63;
    int ln16 = lane & 15, quad = lane >> 4;

    __shared__ ushort Ks[2][64 * 72];   // [key][dim], pad 8
    __shared__ ushort Vt[2][64 * 64];   // [dim][grp^swz][8], no pad
    __shared__ ushort Ps[4][16 * 72];   // per-wave [qrow][key], pad 8

    int skey[2], sc8;
    sc8 = (tid & 7) * 8;
    skey[0] = tid >> 3;
    skey[1] = (256 + tid) >> 3;

    short8 kst[2], vst[2];
    const ushort* kbase = qkv + DIM + head * HD + sc8;

    short8 qf[2];
    {
        const ushort* qp = &qkv[(size_t)(qt * 64 + w * 16 + ln16) * QKVD
                                + head * HD + quad * 8];
        qf[0] = *(const short8*)qp;
        qf[1] = *(const short8*)(qp + 32);
    }

#pragma unroll
    for (int hh = 0; hh < 2; ++hh) {
        const ushort* kp = kbase + (size_t)(0 * 64 + skey[hh]) * QKVD;
        kst[hh] = *(const short8*)kp;
        vst[hh] = *(const short8*)(kp + DIM);
    }
#pragma unroll
    for (int hh = 0; hh < 2; ++hh) {
        int key = skey[hh];
        *(short8*)&Ks[0][key * 72 + sc8] = kst[hh];
        int g0 = key >> 3, ke = key & 7;
#pragma unroll
        for (int j = 0; j < 8; ++j) {
            int r = sc8 + j;
            Vt[0][r * 64 + ((g0 ^ (r >> 3)) & 7) * 8 + ke] = ((ushort*)&vst[hh])[j];
        }
    }
    __syncthreads();

    float m_i = -1e30f, l_i = 0.f;
    f32x4 oacc[4];
#pragma unroll
    for (int mt = 0; mt < 4; ++mt) oacc[mt] = {0.f, 0.f, 0.f, 0.f};

    int cur = 0;
    for (int kt = 0; kt <= qt; ++kt) {
        bool pre = (kt < qt);
        if (pre) {
#pragma unroll
            for (int hh = 0; hh < 2; ++hh) {
                const ushort* kp = kbase + (size_t)((kt + 1) * 64 + skey[hh]) * QKVD;
                kst[hh] = *(const short8*)kp;
                vst[hh] = *(const short8*)(kp + DIM);
            }
        }

        f32x4 s[4];
#pragma unroll
        for (int mt = 0; mt < 4; ++mt) {
            s[mt] = {0.f, 0.f, 0.f, 0.f};
#pragma unroll
            for (int kc = 0; kc < 2; ++kc) {
                short8 kf = *(const short8*)&Ks[cur][(mt * 16 + ln16) * 72
                                                     + kc * 32 + quad * 8];
                s[mt] = __builtin_amdgcn_mfma_f32_16x16x32_bf16(
                    kf, qf[kc], s[mt], 0, 0, 0);
            }
        }

        int qrow = qt * 64 + w * 16 + ln16;
        float sv[4][4];
        if (kt == qt) {
#pragma unroll
            for (int mt = 0; mt < 4; ++mt)
#pragma unroll
                for (int r = 0; r < 4; ++r) {
                    int key = kt * 64 + mt * 16 + quad * 4 + r;
                    sv[mt][r] = (key > qrow) ? -1e30f : s[mt][r] * 0.125f;
                }
        } else {
#pragma unroll
            for (int mt = 0; mt < 4; ++mt)
#pragma unroll
                for (int r = 0; r < 4; ++r) sv[mt][r] = s[mt][r] * 0.125f;
        }

        float tmax = -1e30f;
#pragma unroll
        for (int mt = 0; mt < 4; ++mt)
#pragma unroll
            for (int r = 0; r < 4; ++r) tmax = fmaxf(tmax, sv[mt][r]);
        tmax = fmaxf(tmax, __shfl_xor(tmax, 16));
        tmax = fmaxf(tmax, __shfl_xor(tmax, 32));
        float m_new = fmaxf(m_i, tmax);
        float alpha = __expf(m_i - m_new);
        m_i = m_new;

        float ls = 0.f;
#pragma unroll
        for (int mt = 0; mt < 4; ++mt) {
            union { ushort u[4]; unsigned long long ull; } pk;
#pragma unroll
            for (int r = 0; r < 4; ++r) {
                float p = __expf(sv[mt][r] - m_new);
                ls += p;
                pk.u[r] = bf16bits(p);
            }
            *(unsigned long long*)&Ps[w][ln16 * 72 + mt * 16 + quad * 4] = pk.ull;
        }
        ls += __shfl_xor(ls, 16);
        ls += __shfl_xor(ls, 32);
        l_i = l_i * alpha + ls;

#pragma unroll
        for (int mt = 0; mt < 4; ++mt) {
            oacc[mt][0] *= alpha; oacc[mt][1] *= alpha;
            oacc[mt][2] *= alpha; oacc[mt][3] *= alpha;
        }

#pragma unroll
        for (int kc = 0; kc < 2; ++kc) {
            short8 pf = *(const short8*)&Ps[w][ln16 * 72 + kc * 32 + quad * 8];
#pragma unroll
            for (int mt = 0; mt < 4; ++mt) {
                int row = mt * 16 + ln16;
                int g = kc * 4 + quad;
                short8 vf = *(const short8*)&Vt[cur][row * 64
                                                     + ((g ^ (row >> 3)) & 7) * 8];
                oacc[mt] = __builtin_amdgcn_mfma_f32_16x16x32_bf16(
                    vf, pf, oacc[mt], 0, 0, 0);
            }
        }

        if (pre) {
            int nb = cur ^ 1;
#pragma unroll
            for (int hh = 0; hh < 2; ++hh) {
                int key = skey[hh];
                *(short8*)&Ks[nb][key * 72 + sc8] = kst[hh];
                int g0 = key >> 3, ke = key & 7;
#pragma unroll
                for (int j = 0; j < 8; ++j) {
                    int r = sc8 + j;
                    Vt[nb][r * 64 + ((g0 ^ (r >> 3)) & 7) * 8 + ke] =
                        ((ushort*)&vst[hh])[j];
                }
            }
        }
        __syncthreads();
        cur ^= 1;
    }

    float inv = 1.0f / l_i;
    int orow = qt * 64 + w * 16 + ln16;
#pragma unroll
    for (int mt = 0; mt < 4; ++mt)
#pragma unroll
        for (int r = 0; r < 4; ++r) {
            int dimc = head * HD + mt * 16 + quad * 4 + r;
            o[(size_t)orow * DIM + dimc] = bf16bits(oacc[mt][r] * inv);
        }
}

extern "C" void kernel_launch(void* const* d_in, const int* in_sizes, int n_in,
                              void* d_out, int out_size, void* d_ws, size_t ws_size,
                              hipStream_t stream) {
    const int*   idx   = (const int*)  d_in[0];
    const float* emb   = (const float*)d_in[1];
    const float* pe    = (const float*)d_in[2];
    const float* qkv_w = (const float*)d_in[3];
    const float* qkv_b = (const float*)d_in[4];
    const float* out_w = (const float*)d_in[5];
    const float* out_b = (const float*)d_in[6];
    const float* ln1_s = (const float*)d_in[7];
    const float* ln1_b = (const float*)d_in[8];
    const float* ln2_s = (const float*)d_in[9];
    const float* ln2_b = (const float*)d_in[10];
    const float* w1    = (const float*)d_in[11];
    const float* b1    = (const float*)d_in[12];
    const float* w2    = (const float*)d_in[13];
    const float* b2    = (const float*)d_in[14];

    float* x = (float*)d_ws;                                   // [SEQ,DIM] f32
    __hip_bfloat16* h   = (__hip_bfloat16*)(x + SEQ * DIM);    // [SEQ,DIM] bf16 (also o)
    __hip_bfloat16* qkv = h + SEQ * DIM;                       // [SEQ,QKVD]
    __hip_bfloat16* ffa = qkv + (size_t)SEQ * QKVD;            // [SEQ,FFN]
    __hip_bfloat16* qkv_wT = ffa + (size_t)SEQ * FFN;          // [L,QKVD,DIM]
    __hip_bfloat16* out_wT = qkv_wT + (size_t)2 * QKVD * DIM;  // [L,DIM,DIM]
    __hip_bfloat16* w1T    = out_wT + (size_t)2 * DIM * DIM;   // [L,FFN,DIM]
    __hip_bfloat16* w2T    = w1T + (size_t)2 * FFN * DIM;      // [L,DIM,FFN]

    transpose_all<<<19968, 256, 0, stream>>>(qkv_w, out_w, w1, w2,
                                             qkv_wT, out_wT, w1T, w2T,
                                             idx, emb, pe, x);

    for (int l = 0; l < 2; ++l) {
        ln_kernel<<<SEQ, 256, 0, stream>>>(x, ln1_s + l * DIM, ln1_b + l * DIM, h);
        mfma_gemm<128, false, false, true><<<dim3(QKVD / 128, SEQ / 128), 256, 0, stream>>>(
            (const ushort*)h, (const ushort*)(qkv_wT + (size_t)l * QKVD * DIM),
            qkv_b + l * QKVD, nullptr, qkv, SEQ, QKVD, DIM);
        flash_attn_kernel<<<dim3(32 * NH), 256, 0, stream>>>(
            (const ushort*)qkv, (ushort*)h);   // o aliases h
        mfma_gemm<64, false, true, false><<<dim3(DIM / 64, SEQ / 128), 256, 0, stream>>>(
            (const ushort*)h, (const ushort*)(out_wT + (size_t)l * DIM * DIM),
            out_b + l * DIM, x, x, SEQ, DIM, DIM);
        ln_kernel<<<SEQ, 256, 0, stream>>>(x, ln2_s + l * DIM, ln2_b + l * DIM, h);
        mfma_gemm<128, true, false, true><<<dim3(FFN / 128, SEQ / 128), 256, 0, stream>>>(
            (const ushort*)h, (const ushort*)(w1T + (size_t)l * FFN * DIM),
            b1 + l * FFN, nullptr, ffa, SEQ, FFN, DIM);
        float* cdst = (l == 1) ? (float*)d_out : x;
        mfma_gemm<64, false, true, false><<<dim3(DIM / 64, SEQ / 128), 256, 0, stream>>>(
            (const ushort*)ffa, (const ushort*)(w2T + (size_t)l * DIM * FFN),
            b2 + l * DIM, x, cdst, SEQ, DIM, FFN);
    }
}

// Round 6
// 561.260 us; speedup vs baseline: 1.0741x; 1.0741x over previous
//
#include <hip/hip_runtime.h>
#include <hip/hip_bf16.h>

// TransformerShardA: 2-layer GPT-2 shard. B=1, S=2048, D=768, H=12, hd=64,
// FFN=3072. Inputs f32 (+int idx), output f32 [1,2048,768].
//
// Round 12 (session R5->R6): REVERT GEMM to R4-exact (measured 566.0):
//  - BK=64, double-buffered LDS, one __syncthreads per K-step, stage(t+1)
//    issued via global_load_lds before compute(t). (R5's depth-3 counted
//    vmcnt pipeline + BK=32 regressed +37 us: source-level vmcnt pinning
//    defeats compiler scheduling on 2-barrier loops [m131-m141], and BK=32
//    re-doubled barrier count.)
// KEPT from R5 (independent, low-risk):
//  - ln_kernel with 2 barriers (wave shfl_xor reduce + 4-word LDS).
//  - embed merged into transpose_all.
// Attention frozen (R3 state).

#define SEQ 2048
#define DIM 768
#define NH 12
#define HD 64
#define FFN 3072
#define QKVD (3 * DIM)

typedef __attribute__((ext_vector_type(8))) short short8;
typedef __attribute__((ext_vector_type(4))) float f32x4;

__device__ __forceinline__ ushort bf16bits(float v) {
    __hip_bfloat16 hb = __float2bfloat16(v);
    return *reinterpret_cast<ushort*>(&hb);
}

// async 16B global->LDS (gfx950 global_load_lds_dwordx4)
__device__ __forceinline__ void gload_lds16(const ushort* g, ushort* l) {
    __builtin_amdgcn_global_load_lds(
        (const __attribute__((address_space(1))) void*)g,
        (__attribute__((address_space(3))) void*)l, 16, 0, 0);
}

// ------- merged: weight transpose W[K,N] f32 -> WT[N,K] bf16, + embedding ---
// blocks [0,13824): transposes. blocks [13824,19968): embed (x = emb[idx]+pe).
__global__ void transpose_all(
        const float* __restrict__ qkv_w, const float* __restrict__ out_w,
        const float* __restrict__ w1, const float* __restrict__ w2,
        __hip_bfloat16* __restrict__ qkv_wT, __hip_bfloat16* __restrict__ out_wT,
        __hip_bfloat16* __restrict__ w1T, __hip_bfloat16* __restrict__ w2T,
        const int* __restrict__ idx, const float* __restrict__ emb,
        const float* __restrict__ pe, float* __restrict__ x) {
    int b = blockIdx.x;
    if (b >= 13824) {                       // ---- embedding ----
        int i = (b - 13824) * 256 + threadIdx.x;
        int s = i / DIM;
        int d = i - s * DIM;
        x[i] = emb[idx[s] * DIM + d] + pe[i];
        return;
    }
    __shared__ float t[32][33];
    const float* W; __hip_bfloat16* T; int K, N, nx;
    if (b < 3456)        { W = qkv_w; T = qkv_wT; K = 768;  N = 2304; nx = 72; }
    else if (b < 4608)   { b -= 3456; W = out_w; T = out_wT; K = 768; N = 768; nx = 24; }
    else if (b < 9216)   { b -= 4608; W = w1;    T = w1T;   K = 768;  N = 3072; nx = 96; }
    else                 { b -= 9216; W = w2;    T = w2T;   K = 3072; N = 768;  nx = 24; }
    int ny = K / 32;
    int bz = b / (nx * ny);
    int rem = b - bz * (nx * ny);
    int by = rem / nx, bx = rem - by * nx;

    const float* Wp = W + (size_t)bz * K * N;
    __hip_bfloat16* Tp = T + (size_t)bz * K * N;
    int k0 = by * 32, n0 = bx * 32;
    int r = threadIdx.x >> 3, c4 = (threadIdx.x & 7) * 4;
    float4 v = *(const float4*)&Wp[(size_t)(k0 + r) * N + n0 + c4];
    t[r][c4 + 0] = v.x; t[r][c4 + 1] = v.y; t[r][c4 + 2] = v.z; t[r][c4 + 3] = v.w;
    __syncthreads();
    __hip_bfloat16* dst = &Tp[(size_t)(n0 + r) * K + k0 + c4];
#pragma unroll
    for (int j = 0; j < 4; ++j) dst[j] = __float2bfloat16(t[c4 + j][r]);
}

// ---------------- LayerNorm (one block per row), writes bf16 ----------------
// wave shfl_xor reduction + 4-word LDS: 2 barriers total.
__global__ void ln_kernel(const float* __restrict__ x,
                          const float* __restrict__ sc,
                          const float* __restrict__ bi,
                          __hip_bfloat16* __restrict__ h) {
    int row = blockIdx.x, tid = threadIdx.x;
    int w = tid >> 6;
    int lane = tid & 63;
    __shared__ float ws[4], ws2[4];
    const float* xr = x + row * DIM;
    float v[3];
#pragma unroll
    for (int i = 0; i < 3; ++i) v[i] = xr[tid + i * 256];
    float s = v[0] + v[1] + v[2];
#pragma unroll
    for (int off = 32; off > 0; off >>= 1) s += __shfl_xor(s, off);
    if (lane == 0) ws[w] = s;
    __syncthreads();
    float mean = (ws[0] + ws[1] + ws[2] + ws[3]) * (1.0f / DIM);
    float q = 0.f;
#pragma unroll
    for (int i = 0; i < 3; ++i) { float d = v[i] - mean; q += d * d; }
#pragma unroll
    for (int off = 32; off > 0; off >>= 1) q += __shfl_xor(q, off);
    if (lane == 0) ws2[w] = q;
    __syncthreads();
    float rstd = rsqrtf((ws2[0] + ws2[1] + ws2[2] + ws2[3]) * (1.0f / DIM) + 1e-5f);
#pragma unroll
    for (int i = 0; i < 3; ++i) {
        int d = tid + i * 256;
        h[row * DIM + d] = __float2bfloat16((v[i] - mean) * rstd * sc[d] + bi[d]);
    }
}

// ---------------- bf16 MFMA GEMM: C = [res +] act(A@W + bias) ---------------
// 128xBN tile, 4 waves (2x2), BK=64, double-buffered LDS, 1 barrier/K-step.
// LDS layout: [row][8 chunks of 16B], chunk XOR-swizzled j' = j ^ (row&7).
// Staging: gload_lds writes chunk c linearly; global source pre-swizzled
// (col chunk = (c&7) ^ ((c>>3)&7)), so LDS holds the swizzled layout.
// Frag reads XOR with (lm&7).
template <int BN, bool GELU, bool RES, bool OUTBF16>
__global__ __launch_bounds__(256) void mfma_gemm(
        const ushort* __restrict__ A, const ushort* __restrict__ WT,
        const float* __restrict__ bias, const float* __restrict__ res,
        void* __restrict__ Cout, int M, int N, int K) {
    constexpr int NT = BN / 32;          // B-frags per wave: 4 or 2
    constexpr int NBC = BN * 8 / 256;    // B chunks per thread: 4 or 2
    __shared__ ushort As[2][128 * 64];
    __shared__ ushort Bs[2][BN * 64];
    int tid = threadIdx.x;
    int w = tid >> 6, lane = tid & 63;
    int wm = (w >> 1) * 64, wn = (w & 1) * (BN / 2);
    int bm = blockIdx.y * 128, bn = blockIdx.x * BN;
    int lm = lane & 15, quad = lane >> 4;
    int jb = lm & 7;                     // frag-read swizzle key

    f32x4 acc[4][NT];
#pragma unroll
    for (int i = 0; i < 4; ++i)
#pragma unroll
        for (int j = 0; j < NT; ++j) acc[i][j] = {0.f, 0.f, 0.f, 0.f};

    // staging pointers: chunk c = i*256 + tid; row = c>>3; swz col chunk
    const ushort* gA[4];
    const ushort* gB[NBC];
#pragma unroll
    for (int i = 0; i < 4; ++i) {
        int c = i * 256 + tid;
        int row = c >> 3, j = (c & 7) ^ (row & 7);
        gA[i] = &A[(size_t)(bm + row) * K + j * 8];
    }
#pragma unroll
    for (int i = 0; i < NBC; ++i) {
        int c = i * 256 + tid;
        int row = c >> 3, j = (c & 7) ^ (row & 7);
        gB[i] = &WT[(size_t)(bn + row) * K + j * 8];
    }

    const int nk = K >> 6;

    // prologue: stage K-step 0 into buffer 0
#pragma unroll
    for (int i = 0; i < 4; ++i)
        gload_lds16(gA[i], &As[0][(i * 256 + tid) * 8]);
#pragma unroll
    for (int i = 0; i < NBC; ++i)
        gload_lds16(gB[i], &Bs[0][(i * 256 + tid) * 8]);
    __syncthreads();

    int p = 0;
    for (int t = 0; t < nk; ++t) {
        // stage next K-step into the other buffer (loads fly during compute)
        if (t + 1 < nk) {
            int k1 = (t + 1) << 6;
#pragma unroll
            for (int i = 0; i < 4; ++i)
                gload_lds16(gA[i] + k1, &As[p ^ 1][(i * 256 + tid) * 8]);
#pragma unroll
            for (int i = 0; i < NBC; ++i)
                gload_lds16(gB[i] + k1, &Bs[p ^ 1][(i * 256 + tid) * 8]);
        }

        // frag reads (XOR-swizzled) + 2x K=32 MFMA sub-steps
        short8 af[2][4], bw[2][NT];
#pragma unroll
        for (int kc = 0; kc < 2; ++kc) {
#pragma unroll
            for (int mt = 0; mt < 4; ++mt) {
                int row = wm + mt * 16 + lm;
                int j = (kc * 4 + quad) ^ jb;
                af[kc][mt] = *(const short8*)&As[p][row * 64 + j * 8];
            }
#pragma unroll
            for (int nt = 0; nt < NT; ++nt) {
                int row = wn + nt * 16 + lm;
                int j = (kc * 4 + quad) ^ jb;
                bw[kc][nt] = *(const short8*)&Bs[p][row * 64 + j * 8];
            }
        }
#pragma unroll
        for (int kc = 0; kc < 2; ++kc)
#pragma unroll
            for (int mt = 0; mt < 4; ++mt)
#pragma unroll
                for (int nt = 0; nt < NT; ++nt)
                    acc[mt][nt] = __builtin_amdgcn_mfma_f32_16x16x32_bf16(
                        af[kc][mt], bw[kc][nt], acc[mt][nt], 0, 0, 0);

        __syncthreads();   // drains vmcnt (stage t+1 had full compute to land)
        p ^= 1;
    }

    int q8 = quad * 8;
#pragma unroll
    for (int nt = 0; nt < NT; ++nt) {
        int col = bn + wn + nt * 16 + lm;
        float bv = bias[col];
#pragma unroll
        for (int mt = 0; mt < 4; ++mt) {
            int rowb = bm + wm + mt * 16 + (q8 >> 1);
#pragma unroll
            for (int r = 0; r < 4; ++r) {
                int row = rowb + r;
                float v = acc[mt][nt][r] + bv;
                if (GELU) v = 0.5f * v * (1.0f + erff(v * 0.70710678118654752f));
                if (RES) v += res[(size_t)row * N + col];
                if (OUTBF16)
                    ((__hip_bfloat16*)Cout)[(size_t)row * N + col] = __float2bfloat16(v);
                else
                    ((float*)Cout)[(size_t)row * N + col] = v;
            }
        }
    }
}

// ---------------- MFMA flash attention (unchanged from R3) ----------------
__global__ __launch_bounds__(256) void flash_attn_kernel(
        const ushort* __restrict__ qkv, ushort* __restrict__ o) {
    int bi = blockIdx.x;
    int qt = 31 - bi / NH, head = bi % NH;
    int tid = threadIdx.x, w = tid >> 6, lane = tid & 63;
    int ln16 = lane & 15, quad = lane >> 4;

    __shared__ ushort Ks[2][64 * 72];   // [key][dim], pad 8
    __shared__ ushort Vt[2][64 * 64];   // [dim][grp^swz][8], no pad
    __shared__ ushort Ps[4][16 * 72];   // per-wave [qrow][key], pad 8

    int skey[2], sc8;
    sc8 = (tid & 7) * 8;
    skey[0] = tid >> 3;
    skey[1] = (256 + tid) >> 3;

    short8 kst[2], vst[2];
    const ushort* kbase = qkv + DIM + head * HD + sc8;

    short8 qf[2];
    {
        const ushort* qp = &qkv[(size_t)(qt * 64 + w * 16 + ln16) * QKVD
                                + head * HD + quad * 8];
        qf[0] = *(const short8*)qp;
        qf[1] = *(const short8*)(qp + 32);
    }

#pragma unroll
    for (int hh = 0; hh < 2; ++hh) {
        const ushort* kp = kbase + (size_t)(0 * 64 + skey[hh]) * QKVD;
        kst[hh] = *(const short8*)kp;
        vst[hh] = *(const short8*)(kp + DIM);
    }
#pragma unroll
    for (int hh = 0; hh < 2; ++hh) {
        int key = skey[hh];
        *(short8*)&Ks[0][key * 72 + sc8] = kst[hh];
        int g0 = key >> 3, ke = key & 7;
#pragma unroll
        for (int j = 0; j < 8; ++j) {
            int r = sc8 + j;
            Vt[0][r * 64 + ((g0 ^ (r >> 3)) & 7) * 8 + ke] = ((ushort*)&vst[hh])[j];
        }
    }
    __syncthreads();

    float m_i = -1e30f, l_i = 0.f;
    f32x4 oacc[4];
#pragma unroll
    for (int mt = 0; mt < 4; ++mt) oacc[mt] = {0.f, 0.f, 0.f, 0.f};

    int cur = 0;
    for (int kt = 0; kt <= qt; ++kt) {
        bool pre = (kt < qt);
        if (pre) {
#pragma unroll
            for (int hh = 0; hh < 2; ++hh) {
                const ushort* kp = kbase + (size_t)((kt + 1) * 64 + skey[hh]) * QKVD;
                kst[hh] = *(const short8*)kp;
                vst[hh] = *(const short8*)(kp + DIM);
            }
        }

        f32x4 s[4];
#pragma unroll
        for (int mt = 0; mt < 4; ++mt) {
            s[mt] = {0.f, 0.f, 0.f, 0.f};
#pragma unroll
            for (int kc = 0; kc < 2; ++kc) {
                short8 kf = *(const short8*)&Ks[cur][(mt * 16 + ln16) * 72
                                                     + kc * 32 + quad * 8];
                s[mt] = __builtin_amdgcn_mfma_f32_16x16x32_bf16(
                    kf, qf[kc], s[mt], 0, 0, 0);
            }
        }

        int qrow = qt * 64 + w * 16 + ln16;
        float sv[4][4];
        if (kt == qt) {
#pragma unroll
            for (int mt = 0; mt < 4; ++mt)
#pragma unroll
                for (int r = 0; r < 4; ++r) {
                    int key = kt * 64 + mt * 16 + quad * 4 + r;
                    sv[mt][r] = (key > qrow) ? -1e30f : s[mt][r] * 0.125f;
                }
        } else {
#pragma unroll
            for (int mt = 0; mt < 4; ++mt)
#pragma unroll
                for (int r = 0; r < 4; ++r) sv[mt][r] = s[mt][r] * 0.125f;
        }

        float tmax = -1e30f;
#pragma unroll
        for (int mt = 0; mt < 4; ++mt)
#pragma unroll
            for (int r = 0; r < 4; ++r) tmax = fmaxf(tmax, sv[mt][r]);
        tmax = fmaxf(tmax, __shfl_xor(tmax, 16));
        tmax = fmaxf(tmax, __shfl_xor(tmax, 32));
        float m_new = fmaxf(m_i, tmax);
        float alpha = __expf(m_i - m_new);
        m_i = m_new;

        float ls = 0.f;
#pragma unroll
        for (int mt = 0; mt < 4; ++mt) {
            union { ushort u[4]; unsigned long long ull; } pk;
#pragma unroll
            for (int r = 0; r < 4; ++r) {
                float p = __expf(sv[mt][r] - m_new);
                ls += p;
                pk.u[r] = bf16bits(p);
            }
            *(unsigned long long*)&Ps[w][ln16 * 72 + mt * 16 + quad * 4] = pk.ull;
        }
        ls += __shfl_xor(ls, 16);
        ls += __shfl_xor(ls, 32);
        l_i = l_i * alpha + ls;

#pragma unroll
        for (int mt = 0; mt < 4; ++mt) {
            oacc[mt][0] *= alpha; oacc[mt][1] *= alpha;
            oacc[mt][2] *= alpha; oacc[mt][3] *= alpha;
        }

#pragma unroll
        for (int kc = 0; kc < 2; ++kc) {
            short8 pf = *(const short8*)&Ps[w][ln16 * 72 + kc * 32 + quad * 8];
#pragma unroll
            for (int mt = 0; mt < 4; ++mt) {
                int row = mt * 16 + ln16;
                int g = kc * 4 + quad;
                short8 vf = *(const short8*)&Vt[cur][row * 64
                                                     + ((g ^ (row >> 3)) & 7) * 8];
                oacc[mt] = __builtin_amdgcn_mfma_f32_16x16x32_bf16(
                    vf, pf, oacc[mt], 0, 0, 0);
            }
        }

        if (pre) {
            int nb = cur ^ 1;
#pragma unroll
            for (int hh = 0; hh < 2; ++hh) {
                int key = skey[hh];
                *(short8*)&Ks[nb][key * 72 + sc8] = kst[hh];
                int g0 = key >> 3, ke = key & 7;
#pragma unroll
                for (int j = 0; j < 8; ++j) {
                    int r = sc8 + j;
                    Vt[nb][r * 64 + ((g0 ^ (r >> 3)) & 7) * 8 + ke] =
                        ((ushort*)&vst[hh])[j];
                }
            }
        }
        __syncthreads();
        cur ^= 1;
    }

    float inv = 1.0f / l_i;
    int orow = qt * 64 + w * 16 + ln16;
#pragma unroll
    for (int mt = 0; mt < 4; ++mt)
#pragma unroll
        for (int r = 0; r < 4; ++r) {
            int dimc = head * HD + mt * 16 + quad * 4 + r;
            o[(size_t)orow * DIM + dimc] = bf16bits(oacc[mt][r] * inv);
        }
}

extern "C" void kernel_launch(void* const* d_in, const int* in_sizes, int n_in,
                              void* d_out, int out_size, void* d_ws, size_t ws_size,
                              hipStream_t stream) {
    const int*   idx   = (const int*)  d_in[0];
    const float* emb   = (const float*)d_in[1];
    const float* pe    = (const float*)d_in[2];
    const float* qkv_w = (const float*)d_in[3];
    const float* qkv_b = (const float*)d_in[4];
    const float* out_w = (const float*)d_in[5];
    const float* out_b = (const float*)d_in[6];
    const float* ln1_s = (const float*)d_in[7];
    const float* ln1_b = (const float*)d_in[8];
    const float* ln2_s = (const float*)d_in[9];
    const float* ln2_b = (const float*)d_in[10];
    const float* w1    = (const float*)d_in[11];
    const float* b1    = (const float*)d_in[12];
    const float* w2    = (const float*)d_in[13];
    const float* b2    = (const float*)d_in[14];

    float* x = (float*)d_ws;                                   // [SEQ,DIM] f32
    __hip_bfloat16* h   = (__hip_bfloat16*)(x + SEQ * DIM);    // [SEQ,DIM] bf16 (also o)
    __hip_bfloat16* qkv = h + SEQ * DIM;                       // [SEQ,QKVD]
    __hip_bfloat16* ffa = qkv + (size_t)SEQ * QKVD;            // [SEQ,FFN]
    __hip_bfloat16* qkv_wT = ffa + (size_t)SEQ * FFN;          // [L,QKVD,DIM]
    __hip_bfloat16* out_wT = qkv_wT + (size_t)2 * QKVD * DIM;  // [L,DIM,DIM]
    __hip_bfloat16* w1T    = out_wT + (size_t)2 * DIM * DIM;   // [L,FFN,DIM]
    __hip_bfloat16* w2T    = w1T + (size_t)2 * FFN * DIM;      // [L,DIM,FFN]

    transpose_all<<<19968, 256, 0, stream>>>(qkv_w, out_w, w1, w2,
                                             qkv_wT, out_wT, w1T, w2T,
                                             idx, emb, pe, x);

    for (int l = 0; l < 2; ++l) {
        ln_kernel<<<SEQ, 256, 0, stream>>>(x, ln1_s + l * DIM, ln1_b + l * DIM, h);
        mfma_gemm<128, false, false, true><<<dim3(QKVD / 128, SEQ / 128), 256, 0, stream>>>(
            (const ushort*)h, (const ushort*)(qkv_wT + (size_t)l * QKVD * DIM),
            qkv_b + l * QKVD, nullptr, qkv, SEQ, QKVD, DIM);
        flash_attn_kernel<<<dim3(32 * NH), 256, 0, stream>>>(
            (const ushort*)qkv, (ushort*)h);   // o aliases h
        mfma_gemm<64, false, true, false><<<dim3(DIM / 64, SEQ / 128), 256, 0, stream>>>(
            (const ushort*)h, (const ushort*)(out_wT + (size_t)l * DIM * DIM),
            out_b + l * DIM, x, x, SEQ, DIM, DIM);
        ln_kernel<<<SEQ, 256, 0, stream>>>(x, ln2_s + l * DIM, ln2_b + l * DIM, h);
        mfma_gemm<128, true, false, true><<<dim3(FFN / 128, SEQ / 128), 256, 0, stream>>>(
            (const ushort*)h, (const ushort*)(w1T + (size_t)l * FFN * DIM),
            b1 + l * FFN, nullptr, ffa, SEQ, FFN, DIM);
        float* cdst = (l == 1) ? (float*)d_out : x;
        mfma_gemm<64, false, true, false><<<dim3(DIM / 64, SEQ / 128), 256, 0, stream>>>(
            (const ushort*)ffa, (const ushort*)(w2T + (size_t)l * DIM * FFN),
            b2 + l * DIM, x, cdst, SEQ, DIM, FFN);
    }
}

// Round 7
// 559.337 us; speedup vs baseline: 1.0778x; 1.0034x over previous
//
#include <hip/hip_runtime.h>
#include <hip/hip_bf16.h>

// TransformerShardA: 2-layer GPT-2 shard. B=1, S=2048, D=768, H=12, hd=64,
// FFN=3072. Inputs f32 (+int idx), output f32 [1,2048,768].
//
// Round 13 (session R6->R7): locality pass on the R6-proven structure.
//  - T1 bijective XCD swizzle in all GEMMs (flat grid, lid=(bid&7)*cpx+bid>>3,
//    bx=lid%nx): the 12-24 consecutive blocks sharing an A-panel now land on
//    ONE XCD L2 instead of round-robin over 8 (ffn2 A-panel dup was ~8x).
//    All GEMM grids divisible by 8 -> simple swizzle is bijective.
//  - same swizzle for attention (KV head panels 512 KB shared by 32 blocks;
//    all 384 blocks co-resident so dispatch order is irrelevant).
//  - ln_kernel vectorized (G13): 192 threads, float4 loads, ushort4 stores.
// GEMM inner structure/schedule unchanged from R6 (measured 561.3).

#define SEQ 2048
#define DIM 768
#define NH 12
#define HD 64
#define FFN 3072
#define QKVD (3 * DIM)

typedef __attribute__((ext_vector_type(8))) short short8;
typedef __attribute__((ext_vector_type(4))) float f32x4;

__device__ __forceinline__ ushort bf16bits(float v) {
    __hip_bfloat16 hb = __float2bfloat16(v);
    return *reinterpret_cast<ushort*>(&hb);
}

// async 16B global->LDS (gfx950 global_load_lds_dwordx4)
__device__ __forceinline__ void gload_lds16(const ushort* g, ushort* l) {
    __builtin_amdgcn_global_load_lds(
        (const __attribute__((address_space(1))) void*)g,
        (__attribute__((address_space(3))) void*)l, 16, 0, 0);
}

// ------- merged: weight transpose W[K,N] f32 -> WT[N,K] bf16, + embedding ---
// blocks [0,13824): transposes. blocks [13824,19968): embed (x = emb[idx]+pe).
__global__ void transpose_all(
        const float* __restrict__ qkv_w, const float* __restrict__ out_w,
        const float* __restrict__ w1, const float* __restrict__ w2,
        __hip_bfloat16* __restrict__ qkv_wT, __hip_bfloat16* __restrict__ out_wT,
        __hip_bfloat16* __restrict__ w1T, __hip_bfloat16* __restrict__ w2T,
        const int* __restrict__ idx, const float* __restrict__ emb,
        const float* __restrict__ pe, float* __restrict__ x) {
    int b = blockIdx.x;
    if (b >= 13824) {                       // ---- embedding ----
        int i = (b - 13824) * 256 + threadIdx.x;
        int s = i / DIM;
        int d = i - s * DIM;
        x[i] = emb[idx[s] * DIM + d] + pe[i];
        return;
    }
    __shared__ float t[32][33];
    const float* W; __hip_bfloat16* T; int K, N, nx;
    if (b < 3456)        { W = qkv_w; T = qkv_wT; K = 768;  N = 2304; nx = 72; }
    else if (b < 4608)   { b -= 3456; W = out_w; T = out_wT; K = 768; N = 768; nx = 24; }
    else if (b < 9216)   { b -= 4608; W = w1;    T = w1T;   K = 768;  N = 3072; nx = 96; }
    else                 { b -= 9216; W = w2;    T = w2T;   K = 3072; N = 768;  nx = 24; }
    int ny = K / 32;
    int bz = b / (nx * ny);
    int rem = b - bz * (nx * ny);
    int by = rem / nx, bx = rem - by * nx;

    const float* Wp = W + (size_t)bz * K * N;
    __hip_bfloat16* Tp = T + (size_t)bz * K * N;
    int k0 = by * 32, n0 = bx * 32;
    int r = threadIdx.x >> 3, c4 = (threadIdx.x & 7) * 4;
    float4 v = *(const float4*)&Wp[(size_t)(k0 + r) * N + n0 + c4];
    t[r][c4 + 0] = v.x; t[r][c4 + 1] = v.y; t[r][c4 + 2] = v.z; t[r][c4 + 3] = v.w;
    __syncthreads();
    __hip_bfloat16* dst = &Tp[(size_t)(n0 + r) * K + k0 + c4];
#pragma unroll
    for (int j = 0; j < 4; ++j) dst[j] = __float2bfloat16(t[c4 + j][r]);
}

// ---------------- LayerNorm (one block per row), writes bf16 ----------------
// 192 threads (3 waves), float4 loads, ushort4 stores, 2 barriers.
__global__ void ln_kernel(const float* __restrict__ x,
                          const float* __restrict__ sc,
                          const float* __restrict__ bi,
                          __hip_bfloat16* __restrict__ h) {
    int row = blockIdx.x, tid = threadIdx.x;
    int w = tid >> 6;
    int lane = tid & 63;
    __shared__ float ws[3], ws2[3];
    const float4 v = *(const float4*)&x[row * DIM + tid * 4];
    float s = v.x + v.y + v.z + v.w;
#pragma unroll
    for (int off = 32; off > 0; off >>= 1) s += __shfl_xor(s, off);
    if (lane == 0) ws[w] = s;
    __syncthreads();
    float mean = (ws[0] + ws[1] + ws[2]) * (1.0f / DIM);
    float dx = v.x - mean, dy = v.y - mean, dz = v.z - mean, dw = v.w - mean;
    float q = dx * dx + dy * dy + dz * dz + dw * dw;
#pragma unroll
    for (int off = 32; off > 0; off >>= 1) q += __shfl_xor(q, off);
    if (lane == 0) ws2[w] = q;
    __syncthreads();
    float rstd = rsqrtf((ws2[0] + ws2[1] + ws2[2]) * (1.0f / DIM) + 1e-5f);
    const float4 sv = *(const float4*)&sc[tid * 4];
    const float4 bv = *(const float4*)&bi[tid * 4];
    ushort4 o;
    o.x = bf16bits(dx * rstd * sv.x + bv.x);
    o.y = bf16bits(dy * rstd * sv.y + bv.y);
    o.z = bf16bits(dz * rstd * sv.z + bv.z);
    o.w = bf16bits(dw * rstd * sv.w + bv.w);
    *(ushort4*)&h[row * DIM + tid * 4] = o;
}

// ---------------- bf16 MFMA GEMM: C = [res +] act(A@W + bias) ---------------
// 128xBN tile, 4 waves (2x2), BK=64, double-buffered LDS, 1 barrier/K-step.
// Flat grid + bijective XCD swizzle: lid=(bid&7)*(nwg/8)+(bid>>3);
// bx=lid%nx (n-tile), by=lid/nx (m-tile). Consecutive lids share the A-panel
// -> panel stays in one XCD's L2 (grid always divisible by 8 here).
// LDS layout: [row][8 chunks of 16B], chunk XOR-swizzled j' = j ^ (row&7);
// global source pre-swizzled (gload_lds writes linearly), frag reads XOR.
template <int BN, bool GELU, bool RES, bool OUTBF16>
__global__ __launch_bounds__(256) void mfma_gemm(
        const ushort* __restrict__ A, const ushort* __restrict__ WT,
        const float* __restrict__ bias, const float* __restrict__ res,
        void* __restrict__ Cout, int M, int N, int K) {
    constexpr int NT = BN / 32;          // B-frags per wave: 4 or 2
    constexpr int NBC = BN * 8 / 256;    // B chunks per thread: 4 or 2
    __shared__ ushort As[2][128 * 64];
    __shared__ ushort Bs[2][BN * 64];
    int tid = threadIdx.x;
    int w = tid >> 6, lane = tid & 63;
    int wm = (w >> 1) * 64, wn = (w & 1) * (BN / 2);

    // ---- T1 bijective XCD swizzle (nwg % 8 == 0 for all our grids) ----
    int nx = N / BN;
    int nwg = (M / 128) * nx;
    int bid = blockIdx.x;
    int lid = (bid & 7) * (nwg >> 3) + (bid >> 3);
    int bxt = lid % nx, byt = lid / nx;
    int bm = byt * 128, bn = bxt * BN;

    int lm = lane & 15, quad = lane >> 4;
    int jb = lm & 7;                     // frag-read swizzle key

    f32x4 acc[4][NT];
#pragma unroll
    for (int i = 0; i < 4; ++i)
#pragma unroll
        for (int j = 0; j < NT; ++j) acc[i][j] = {0.f, 0.f, 0.f, 0.f};

    // staging pointers: chunk c = i*256 + tid; row = c>>3; swz col chunk
    const ushort* gA[4];
    const ushort* gB[NBC];
#pragma unroll
    for (int i = 0; i < 4; ++i) {
        int c = i * 256 + tid;
        int row = c >> 3, j = (c & 7) ^ (row & 7);
        gA[i] = &A[(size_t)(bm + row) * K + j * 8];
    }
#pragma unroll
    for (int i = 0; i < NBC; ++i) {
        int c = i * 256 + tid;
        int row = c >> 3, j = (c & 7) ^ (row & 7);
        gB[i] = &WT[(size_t)(bn + row) * K + j * 8];
    }

    const int nk = K >> 6;

    // prologue: stage K-step 0 into buffer 0
#pragma unroll
    for (int i = 0; i < 4; ++i)
        gload_lds16(gA[i], &As[0][(i * 256 + tid) * 8]);
#pragma unroll
    for (int i = 0; i < NBC; ++i)
        gload_lds16(gB[i], &Bs[0][(i * 256 + tid) * 8]);
    __syncthreads();

    int p = 0;
    for (int t = 0; t < nk; ++t) {
        // stage next K-step into the other buffer (loads fly during compute)
        if (t + 1 < nk) {
            int k1 = (t + 1) << 6;
#pragma unroll
            for (int i = 0; i < 4; ++i)
                gload_lds16(gA[i] + k1, &As[p ^ 1][(i * 256 + tid) * 8]);
#pragma unroll
            for (int i = 0; i < NBC; ++i)
                gload_lds16(gB[i] + k1, &Bs[p ^ 1][(i * 256 + tid) * 8]);
        }

        // frag reads (XOR-swizzled) + 2x K=32 MFMA sub-steps
        short8 af[2][4], bw[2][NT];
#pragma unroll
        for (int kc = 0; kc < 2; ++kc) {
#pragma unroll
            for (int mt = 0; mt < 4; ++mt) {
                int row = wm + mt * 16 + lm;
                int j = (kc * 4 + quad) ^ jb;
                af[kc][mt] = *(const short8*)&As[p][row * 64 + j * 8];
            }
#pragma unroll
            for (int nt = 0; nt < NT; ++nt) {
                int row = wn + nt * 16 + lm;
                int j = (kc * 4 + quad) ^ jb;
                bw[kc][nt] = *(const short8*)&Bs[p][row * 64 + j * 8];
            }
        }
#pragma unroll
        for (int kc = 0; kc < 2; ++kc)
#pragma unroll
            for (int mt = 0; mt < 4; ++mt)
#pragma unroll
                for (int nt = 0; nt < NT; ++nt)
                    acc[mt][nt] = __builtin_amdgcn_mfma_f32_16x16x32_bf16(
                        af[kc][mt], bw[kc][nt], acc[mt][nt], 0, 0, 0);

        __syncthreads();   // drains vmcnt (stage t+1 had full compute to land)
        p ^= 1;
    }

    int q8 = quad * 8;
#pragma unroll
    for (int nt = 0; nt < NT; ++nt) {
        int col = bn + wn + nt * 16 + lm;
        float bv = bias[col];
#pragma unroll
        for (int mt = 0; mt < 4; ++mt) {
            int rowb = bm + wm + mt * 16 + (q8 >> 1);
#pragma unroll
            for (int r = 0; r < 4; ++r) {
                int row = rowb + r;
                float v = acc[mt][nt][r] + bv;
                if (GELU) v = 0.5f * v * (1.0f + erff(v * 0.70710678118654752f));
                if (RES) v += res[(size_t)row * N + col];
                if (OUTBF16)
                    ((__hip_bfloat16*)Cout)[(size_t)row * N + col] = __float2bfloat16(v);
                else
                    ((float*)Cout)[(size_t)row * N + col] = v;
            }
        }
    }
}

// ---------------- MFMA flash attention ----------------
// R3 structure; block mapping now XCD-swizzled: logical l=(bid&7)*48+(bid>>3),
// head = l>>5 (32 consecutive logical blocks = one head -> KV panel stays in
// one XCD L2), qt = 31-(l&31). All 384 blocks co-resident (43KB LDS) so
// dispatch order is load-balance-irrelevant.
__global__ __launch_bounds__(256) void flash_attn_kernel(
        const ushort* __restrict__ qkv, ushort* __restrict__ o) {
    int bid = blockIdx.x;
    int l = (bid & 7) * 48 + (bid >> 3);
    int head = l >> 5;
    int qt = 31 - (l & 31);
    int tid = threadIdx.x, w = tid >> 6, lane = tid & 63;
    int ln16 = lane & 15, quad = lane >> 4;

    __shared__ ushort Ks[2][64 * 72];   // [key][dim], pad 8
    __shared__ ushort Vt[2][64 * 64];   // [dim][grp^swz][8], no pad
    __shared__ ushort Ps[4][16 * 72];   // per-wave [qrow][key], pad 8

    int skey[2], sc8;
    sc8 = (tid & 7) * 8;
    skey[0] = tid >> 3;
    skey[1] = (256 + tid) >> 3;

    short8 kst[2], vst[2];
    const ushort* kbase = qkv + DIM + head * HD + sc8;

    short8 qf[2];
    {
        const ushort* qp = &qkv[(size_t)(qt * 64 + w * 16 + ln16) * QKVD
                                + head * HD + quad * 8];
        qf[0] = *(const short8*)qp;
        qf[1] = *(const short8*)(qp + 32);
    }

#pragma unroll
    for (int hh = 0; hh < 2; ++hh) {
        const ushort* kp = kbase + (size_t)(0 * 64 + skey[hh]) * QKVD;
        kst[hh] = *(const short8*)kp;
        vst[hh] = *(const short8*)(kp + DIM);
    }
#pragma unroll
    for (int hh = 0; hh < 2; ++hh) {
        int key = skey[hh];
        *(short8*)&Ks[0][key * 72 + sc8] = kst[hh];
        int g0 = key >> 3, ke = key & 7;
#pragma unroll
        for (int j = 0; j < 8; ++j) {
            int r = sc8 + j;
            Vt[0][r * 64 + ((g0 ^ (r >> 3)) & 7) * 8 + ke] = ((ushort*)&vst[hh])[j];
        }
    }
    __syncthreads();

    float m_i = -1e30f, l_i = 0.f;
    f32x4 oacc[4];
#pragma unroll
    for (int mt = 0; mt < 4; ++mt) oacc[mt] = {0.f, 0.f, 0.f, 0.f};

    int cur = 0;
    for (int kt = 0; kt <= qt; ++kt) {
        bool pre = (kt < qt);
        if (pre) {
#pragma unroll
            for (int hh = 0; hh < 2; ++hh) {
                const ushort* kp = kbase + (size_t)((kt + 1) * 64 + skey[hh]) * QKVD;
                kst[hh] = *(const short8*)kp;
                vst[hh] = *(const short8*)(kp + DIM);
            }
        }

        f32x4 s[4];
#pragma unroll
        for (int mt = 0; mt < 4; ++mt) {
            s[mt] = {0.f, 0.f, 0.f, 0.f};
#pragma unroll
            for (int kc = 0; kc < 2; ++kc) {
                short8 kf = *(const short8*)&Ks[cur][(mt * 16 + ln16) * 72
                                                     + kc * 32 + quad * 8];
                s[mt] = __builtin_amdgcn_mfma_f32_16x16x32_bf16(
                    kf, qf[kc], s[mt], 0, 0, 0);
            }
        }

        int qrow = qt * 64 + w * 16 + ln16;
        float sv[4][4];
        if (kt == qt) {
#pragma unroll
            for (int mt = 0; mt < 4; ++mt)
#pragma unroll
                for (int r = 0; r < 4; ++r) {
                    int key = kt * 64 + mt * 16 + quad * 4 + r;
                    sv[mt][r] = (key > qrow) ? -1e30f : s[mt][r] * 0.125f;
                }
        } else {
#pragma unroll
            for (int mt = 0; mt < 4; ++mt)
#pragma unroll
                for (int r = 0; r < 4; ++r) sv[mt][r] = s[mt][r] * 0.125f;
        }

        float tmax = -1e30f;
#pragma unroll
        for (int mt = 0; mt < 4; ++mt)
#pragma unroll
            for (int r = 0; r < 4; ++r) tmax = fmaxf(tmax, sv[mt][r]);
        tmax = fmaxf(tmax, __shfl_xor(tmax, 16));
        tmax = fmaxf(tmax, __shfl_xor(tmax, 32));
        float m_new = fmaxf(m_i, tmax);
        float alpha = __expf(m_i - m_new);
        m_i = m_new;

        float ls = 0.f;
#pragma unroll
        for (int mt = 0; mt < 4; ++mt) {
            union { ushort u[4]; unsigned long long ull; } pk;
#pragma unroll
            for (int r = 0; r < 4; ++r) {
                float p = __expf(sv[mt][r] - m_new);
                ls += p;
                pk.u[r] = bf16bits(p);
            }
            *(unsigned long long*)&Ps[w][ln16 * 72 + mt * 16 + quad * 4] = pk.ull;
        }
        ls += __shfl_xor(ls, 16);
        ls += __shfl_xor(ls, 32);
        l_i = l_i * alpha + ls;

#pragma unroll
        for (int mt = 0; mt < 4; ++mt) {
            oacc[mt][0] *= alpha; oacc[mt][1] *= alpha;
            oacc[mt][2] *= alpha; oacc[mt][3] *= alpha;
        }

#pragma unroll
        for (int kc = 0; kc < 2; ++kc) {
            short8 pf = *(const short8*)&Ps[w][ln16 * 72 + kc * 32 + quad * 8];
#pragma unroll
            for (int mt = 0; mt < 4; ++mt) {
                int row = mt * 16 + ln16;
                int g = kc * 4 + quad;
                short8 vf = *(const short8*)&Vt[cur][row * 64
                                                     + ((g ^ (row >> 3)) & 7) * 8];
                oacc[mt] = __builtin_amdgcn_mfma_f32_16x16x32_bf16(
                    vf, pf, oacc[mt], 0, 0, 0);
            }
        }

        if (pre) {
            int nb = cur ^ 1;
#pragma unroll
            for (int hh = 0; hh < 2; ++hh) {
                int key = skey[hh];
                *(short8*)&Ks[nb][key * 72 + sc8] = kst[hh];
                int g0 = key >> 3, ke = key & 7;
#pragma unroll
                for (int j = 0; j < 8; ++j) {
                    int r = sc8 + j;
                    Vt[nb][r * 64 + ((g0 ^ (r >> 3)) & 7) * 8 + ke] =
                        ((ushort*)&vst[hh])[j];
                }
            }
        }
        __syncthreads();
        cur ^= 1;
    }

    float inv = 1.0f / l_i;
    int orow = qt * 64 + w * 16 + ln16;
#pragma unroll
    for (int mt = 0; mt < 4; ++mt)
#pragma unroll
        for (int r = 0; r < 4; ++r) {
            int dimc = head * HD + mt * 16 + quad * 4 + r;
            o[(size_t)orow * DIM + dimc] = bf16bits(oacc[mt][r] * inv);
        }
}

extern "C" void kernel_launch(void* const* d_in, const int* in_sizes, int n_in,
                              void* d_out, int out_size, void* d_ws, size_t ws_size,
                              hipStream_t stream) {
    const int*   idx   = (const int*)  d_in[0];
    const float* emb   = (const float*)d_in[1];
    const float* pe    = (const float*)d_in[2];
    const float* qkv_w = (const float*)d_in[3];
    const float* qkv_b = (const float*)d_in[4];
    const float* out_w = (const float*)d_in[5];
    const float* out_b = (const float*)d_in[6];
    const float* ln1_s = (const float*)d_in[7];
    const float* ln1_b = (const float*)d_in[8];
    const float* ln2_s = (const float*)d_in[9];
    const float* ln2_b = (const float*)d_in[10];
    const float* w1    = (const float*)d_in[11];
    const float* b1    = (const float*)d_in[12];
    const float* w2    = (const float*)d_in[13];
    const float* b2    = (const float*)d_in[14];

    float* x = (float*)d_ws;                                   // [SEQ,DIM] f32
    __hip_bfloat16* h   = (__hip_bfloat16*)(x + SEQ * DIM);    // [SEQ,DIM] bf16 (also o)
    __hip_bfloat16* qkv = h + SEQ * DIM;                       // [SEQ,QKVD]
    __hip_bfloat16* ffa = qkv + (size_t)SEQ * QKVD;            // [SEQ,FFN]
    __hip_bfloat16* qkv_wT = ffa + (size_t)SEQ * FFN;          // [L,QKVD,DIM]
    __hip_bfloat16* out_wT = qkv_wT + (size_t)2 * QKVD * DIM;  // [L,DIM,DIM]
    __hip_bfloat16* w1T    = out_wT + (size_t)2 * DIM * DIM;   // [L,FFN,DIM]
    __hip_bfloat16* w2T    = w1T + (size_t)2 * FFN * DIM;      // [L,DIM,FFN]

    transpose_all<<<19968, 256, 0, stream>>>(qkv_w, out_w, w1, w2,
                                             qkv_wT, out_wT, w1T, w2T,
                                             idx, emb, pe, x);

    for (int l = 0; l < 2; ++l) {
        ln_kernel<<<SEQ, 192, 0, stream>>>(x, ln1_s + l * DIM, ln1_b + l * DIM, h);
        mfma_gemm<128, false, false, true><<<dim3((QKVD / 128) * (SEQ / 128)), 256, 0, stream>>>(
            (const ushort*)h, (const ushort*)(qkv_wT + (size_t)l * QKVD * DIM),
            qkv_b + l * QKVD, nullptr, qkv, SEQ, QKVD, DIM);
        flash_attn_kernel<<<dim3(32 * NH), 256, 0, stream>>>(
            (const ushort*)qkv, (ushort*)h);   // o aliases h
        mfma_gemm<64, false, true, false><<<dim3((DIM / 64) * (SEQ / 128)), 256, 0, stream>>>(
            (const ushort*)h, (const ushort*)(out_wT + (size_t)l * DIM * DIM),
            out_b + l * DIM, x, x, SEQ, DIM, DIM);
        ln_kernel<<<SEQ, 192, 0, stream>>>(x, ln2_s + l * DIM, ln2_b + l * DIM, h);
        mfma_gemm<128, true, false, true><<<dim3((FFN / 128) * (SEQ / 128)), 256, 0, stream>>>(
            (const ushort*)h, (const ushort*)(w1T + (size_t)l * FFN * DIM),
            b1 + l * FFN, nullptr, ffa, SEQ, FFN, DIM);
        float* cdst = (l == 1) ? (float*)d_out : x;
        mfma_gemm<64, false, true, false><<<dim3((DIM / 64) * (SEQ / 128)), 256, 0, stream>>>(
            (const ushort*)ffa, (const ushort*)(w2T + (size_t)l * DIM * FFN),
            b2 + l * DIM, x, cdst, SEQ, DIM, FFN);
    }
}